// Round 4
// baseline (2418.314 us; speedup 1.0000x reference)
//
#include <hip/hip_runtime.h>
#include <hip/hip_bf16.h>
#include <stdint.h>

#define VOCAB 32000
#define HID 512
#define NB 8
#define SEQ 512
#define NG 1536
#define LN_EPS 1e-5f
#define GRU_WGS 32
#define GRU_SPIN_BUDGET (1 << 20)

typedef short bf16x8 __attribute__((ext_vector_type(8)));
typedef float f32x4 __attribute__((ext_vector_type(4)));

__device__ __forceinline__ unsigned short f2bf(float f) {
  union { float f; uint32_t u; } c; c.f = f;
  return (unsigned short)((c.u + 0x7fffu + ((c.u >> 16) & 1u)) >> 16);
}

// ---------------- init workspace ---------------------------------------------
// h_state = 2 buffers of [16][HID] bf16. Tag bit = bit0 of each u32 word.
// buf0 = h_0 = 0.0 (tag 0 == T(0) -> step-0 readers see it fresh immediately).
// buf1 = 0x00010001 words (tag 1 != T(1)=0 -> step-1 readers wait for writers).
__global__ void init_ws_kernel(unsigned short* h_state) {
  int i = blockIdx.x * 256 + threadIdx.x;
  if (i < 16 * HID) h_state[i] = 0;
  else if (i < 2 * 16 * HID) h_state[i] = 1;
}

// ---------------- fp32 -> bf16 bulk convert ---------------------------------
__global__ void conv_bf16_kernel(const float* __restrict__ in,
                                 unsigned short* __restrict__ out, int n4) {
  int i = blockIdx.x * 256 + threadIdx.x;
  if (i >= n4) return;
  const float4 v = ((const float4*)in)[i];
  ushort4 o;
  o.x = f2bf(v.x); o.y = f2bf(v.y); o.z = f2bf(v.z); o.w = f2bf(v.w);
  ((ushort4*)out)[i] = o;
}

// ---------------- embedding gather -> bf16 A matrix [4096][512] -------------
__global__ void embed_kernel(const int* __restrict__ ids,
                             const float* __restrict__ emb,
                             unsigned short* __restrict__ out) {
  int row = blockIdx.x;
  int id = ids[row];
  int c = threadIdx.x * 2;
  const float2 v = *(const float2*)(emb + (size_t)id * HID + c);
  ushort2 o; o.x = f2bf(v.x); o.y = f2bf(v.y);
  *(ushort2*)(out + (size_t)row * HID + c) = o;
}

// ---------------- bf16 GEMM: C[M][N] = A[M][K] * B[N][K]^T + bias -----------
#define BM 128
#define BN 128
#define BK 32

__global__ __launch_bounds__(256, 2) void gemm_bt_kernel(
    const unsigned short* __restrict__ A, const unsigned short* __restrict__ B,
    const float* __restrict__ bias, float* __restrict__ C, int N, int nbn) {
  __shared__ unsigned short a_lds[BM * BK];
  __shared__ unsigned short b_lds[BN * BK];
  const int nwg = gridDim.x;
  const int chunk = nwg >> 3;
  const int bid = blockIdx.x;
  const int sw = (bid & 7) * chunk + (bid >> 3);
  const int bm = sw / nbn, bn = sw % nbn;
  const int tid = threadIdx.x;
  const int lane = tid & 63, wid = tid >> 6;
  const int wm = wid >> 1, wn = wid & 1;

  f32x4 acc[4][4] = {};

  for (int kt = 0; kt < HID / BK; ++kt) {
    __syncthreads();
#pragma unroll
    for (int p = 0; p < 2; ++p) {
      const int flat = (p * 256 + tid) * 16;  // byte offset in 8KB tile
      const int row = flat >> 6;              // 64B per row (32 bf16)
      const int kb = flat & 63;
      const char* ga =
          (const char*)(A + ((size_t)(bm * BM + row) * HID + kt * BK)) + kb;
      const char* gb =
          (const char*)(B + ((size_t)(bn * BN + row) * HID + kt * BK)) + kb;
      char* la = (char*)a_lds + (size_t)(p * 256 + wid * 64) * 16;
      char* lb = (char*)b_lds + (size_t)(p * 256 + wid * 64) * 16;
      __builtin_amdgcn_global_load_lds(
          (const __attribute__((address_space(1))) void*)ga,
          (__attribute__((address_space(3))) void*)la, 16, 0, 0);
      __builtin_amdgcn_global_load_lds(
          (const __attribute__((address_space(1))) void*)gb,
          (__attribute__((address_space(3))) void*)lb, 16, 0, 0);
    }
    __syncthreads();
    bf16x8 af[4], bfr[4];
#pragma unroll
    for (int i = 0; i < 4; ++i) {
      af[i] = *(const bf16x8*)(a_lds + (wm * 64 + i * 16 + (lane & 15)) * BK +
                               (lane >> 4) * 8);
      bfr[i] = *(const bf16x8*)(b_lds + (wn * 64 + i * 16 + (lane & 15)) * BK +
                                (lane >> 4) * 8);
    }
#pragma unroll
    for (int i = 0; i < 4; ++i)
#pragma unroll
      for (int j = 0; j < 4; ++j)
        acc[i][j] =
            __builtin_amdgcn_mfma_f32_16x16x32_bf16(af[i], bfr[j], acc[i][j], 0, 0, 0);
  }
#pragma unroll
  for (int i = 0; i < 4; ++i) {
    const int mrow = bm * BM + wm * 64 + i * 16 + (lane >> 4) * 4;
#pragma unroll
    for (int j = 0; j < 4; ++j) {
      const int col = bn * BN + wn * 64 + j * 16 + (lane & 15);
      const float bv = bias[col];
#pragma unroll
      for (int r = 0; r < 4; ++r)
        C[(size_t)(mrow + r) * N + col] = acc[i][j][r] + bv;
    }
  }
}

// ---------------- persistent GRU scan: tagged-data protocol ------------------
// 32 WGs x 192 threads. WG w owns h cols [w*16, w*16+16). Wave g computes
// gate g's hg slice via MFMA with w_hh rows register-resident as B-frags.
// NO flags, NO fences, NO publish barrier: h is published as bf16 pairs in
// u32 words whose bit0 (LSB of the even-col bf16) carries the 2-step parity
// tag T(s) = (s>>1)&1. Consumers poll exactly the words their A-fragments
// need, re-loading any word whose tag != T(t) (relaxed agent loads = LLC,
// per-dword atomic). Max cross-WG skew is 1 step (a WG can publish h_{t+2}
// only after all WGs published h_{t+1}), so 1 tag bit disambiguates the two
// generations sharing each double-buffer slot. Critical path per step:
// publish-store visible + consumer poll-load = 2 LLC hops (was 4).
__global__ __launch_bounds__(192, 1) void gru_kernel(
    const float* __restrict__ xg, const float* __restrict__ w_hh,
    const float* __restrict__ b_hh, float* __restrict__ hs,
    unsigned short* h_state) {
  const int wid = blockIdx.x;
  const int tid = threadIdx.x;
  const int lane = tid & 63;
  const int g = tid >> 6;

  __shared__ float hg_lds[3 * 128];
  __shared__ float bhh_lds[48];

  // pack weights into MFMA B-fragments (registers), once
  bf16x8 wf[16];
  {
    const int row = g * HID + wid * 16 + (lane & 15);
    const float* wr = w_hh + (size_t)row * HID + (lane >> 4) * 8;
#pragma unroll
    for (int kk = 0; kk < 16; ++kk) {
      float4 f0 = *(const float4*)(wr + kk * 32);
      float4 f1 = *(const float4*)(wr + kk * 32 + 4);
      bf16x8 v;
      v[0] = (short)f2bf(f0.x); v[1] = (short)f2bf(f0.y);
      v[2] = (short)f2bf(f0.z); v[3] = (short)f2bf(f0.w);
      v[4] = (short)f2bf(f1.x); v[5] = (short)f2bf(f1.y);
      v[6] = (short)f2bf(f1.z); v[7] = (short)f2bf(f1.w);
      wf[kk] = v;
    }
  }
  if (tid < 48) bhh_lds[tid] = b_hh[(tid >> 4) * HID + wid * 16 + (tid & 15)];
  __syncthreads();

  const int abase = (lane & 15) * HID + (lane >> 4) * 8;  // bf16-elem index
  const bool realrow = (lane & 15) < 8;  // batches 8..15 are structural zeros
  const int b8 = tid >> 4, n16 = tid & 15;
  const size_t xoff0 = (size_t)b8 * SEQ * NG + wid * 16 + n16;

  float xr = 0.f, xz = 0.f, xn = 0.f;
  if (tid < 128) {
    xr = xg[xoff0];
    xz = xg[xoff0 + HID];
    xn = xg[xoff0 + 2 * HID];
  }
  float hprev = 0.f;  // this thread's own h (fp32, register-resident)
  int budget = GRU_SPIN_BUDGET;

  for (int t = 0; t < SEQ; ++t) {
    const unsigned short* rd = h_state + (size_t)(t & 1) * (16 * HID);
    unsigned short* wpub = h_state + (size_t)((t + 1) & 1) * (16 * HID);
    const uint32_t texp = (uint32_t)((t >> 1) & 1);
    const uint32_t tpub = (uint32_t)(((t + 1) >> 1) & 1);

    // poll-load the 32 u64 A-fragment words until both embedded tags match
    uint64_t hb[32];
#pragma unroll
    for (int kk = 0; kk < 32; ++kk) hb[kk] = 0;
    uint32_t stale = realrow ? 0xFFFFFFFFu : 0u;
    while (stale) {
#pragma unroll
      for (int kk = 0; kk < 16; ++kk) {
        const uint64_t* ap = (const uint64_t*)(rd + abase + kk * 32);
        if (stale & (1u << (2 * kk)))
          hb[2 * kk] = __hip_atomic_load(ap, __ATOMIC_RELAXED,
                                         __HIP_MEMORY_SCOPE_AGENT);
        if (stale & (1u << (2 * kk + 1)))
          hb[2 * kk + 1] = __hip_atomic_load(ap + 1, __ATOMIC_RELAXED,
                                             __HIP_MEMORY_SCOPE_AGENT);
      }
#pragma unroll
      for (int kk = 0; kk < 32; ++kk) {
        const uint32_t lo = (uint32_t)hb[kk];
        const uint32_t hi = (uint32_t)(hb[kk] >> 32);
        if ((((lo ^ texp) | (hi ^ texp)) & 1u) == 0u) stale &= ~(1u << kk);
      }
      if (--budget <= 0) break;
    }

    // two independent 8-deep MFMA chains (halved dependency latency)
    f32x4 acc0 = {0.f, 0.f, 0.f, 0.f}, acc1 = {0.f, 0.f, 0.f, 0.f};
#pragma unroll
    for (int kk = 0; kk < 16; kk += 2) {
      union { uint64_t u[2]; bf16x8 v; } c0, c1;
      c0.u[0] = hb[2 * kk];     c0.u[1] = hb[2 * kk + 1];
      c1.u[0] = hb[2 * kk + 2]; c1.u[1] = hb[2 * kk + 3];
      acc0 = __builtin_amdgcn_mfma_f32_16x16x32_bf16(c0.v, wf[kk], acc0, 0, 0, 0);
      acc1 = __builtin_amdgcn_mfma_f32_16x16x32_bf16(c1.v, wf[kk + 1], acc1, 0, 0, 0);
    }
    const f32x4 acc = acc0 + acc1;
    if (lane < 32) {  // real batches m=0..7 live in lanes 0..31
      const int m0 = (lane >> 4) * 4;
#pragma unroll
      for (int r = 0; r < 4; ++r)
        hg_lds[g * 128 + (m0 + r) * 16 + (lane & 15)] = acc[r];
    }
    __syncthreads();
    if (tid < 128) {
      const float hrv = hg_lds[tid] + bhh_lds[n16];
      const float hzv = hg_lds[128 + tid] + bhh_lds[16 + n16];
      const float hnv = hg_lds[256 + tid] + bhh_lds[32 + n16];
      const float r = 1.f / (1.f + __expf(-(xr + hrv)));
      const float z = 1.f / (1.f + __expf(-(xz + hzv)));
      const float a = xn + r * hnv;
      const float e2 = __expf(-2.f * fabsf(a));
      const float nn = copysignf((1.f - e2) / (1.f + e2), a);
      const float hnew = (1.f - z) * nn + z * hprev;
      hprev = hnew;
      hs[((size_t)b8 * SEQ + t) * HID + wid * 16 + n16] = hnew;
      // publish tagged bf16 pair: bit0 of the u32 (= LSB of even-col bf16)
      const float hnb = __shfl_down(hnew, 1);
      if ((n16 & 1) == 0) {
        union { unsigned short s[2]; uint32_t u; } pk;
        pk.s[0] = (unsigned short)((f2bf(hnew) & ~(unsigned short)1) | tpub);
        pk.s[1] = f2bf(hnb);
        uint32_t* dst = (uint32_t*)(wpub + b8 * HID + wid * 16 + n16);
        __hip_atomic_store(dst, pk.u, __ATOMIC_RELAXED,
                           __HIP_MEMORY_SCOPE_AGENT);
      }
    }
    // prefetch next xg (completes under the next poll phase)
    if (tid < 128 && t + 1 < SEQ) {
      const size_t xo = xoff0 + (size_t)(t + 1) * NG;
      xr = xg[xo]; xz = xg[xo + HID]; xn = xg[xo + 2 * HID];
    }
    __syncthreads();  // protect hg_lds before next iteration's writes
  }
}

// ---------------- LayerNorm rows of 512 -> bf16 ------------------------------
__global__ __launch_bounds__(256) void ln_kernel(
    const float* __restrict__ hs, const float* __restrict__ gamma,
    const float* __restrict__ beta, unsigned short* __restrict__ y) {
  const int row = blockIdx.x * 4 + (threadIdx.x >> 6);
  const int lane = threadIdx.x & 63;
  const float* x = hs + (size_t)row * HID + lane * 8;
  float v[8];
  *(float4*)v = *(const float4*)x;
  *(float4*)(v + 4) = *(const float4*)(x + 4);
  float s = 0.f, q = 0.f;
#pragma unroll
  for (int j = 0; j < 8; ++j) { s += v[j]; q += v[j] * v[j]; }
#pragma unroll
  for (int off = 32; off > 0; off >>= 1) {
    s += __shfl_xor(s, off);
    q += __shfl_xor(q, off);
  }
  const float mu = s * (1.f / 512.f);
  const float is = rsqrtf(q * (1.f / 512.f) - mu * mu + LN_EPS);
  const float* gp = gamma + lane * 8;
  const float* bp = beta + lane * 8;
  union { unsigned short o[8]; uint4 u; } pk;
#pragma unroll
  for (int j = 0; j < 8; ++j) pk.o[j] = f2bf((v[j] - mu) * is * gp[j] + bp[j]);
  *(uint4*)(y + (size_t)row * HID + lane * 8) = pk.u;
}

// ---------------- launch -----------------------------------------------------
extern "C" void kernel_launch(void* const* d_in, const int* in_sizes, int n_in,
                              void* d_out, int out_size, void* d_ws,
                              size_t ws_size, hipStream_t stream) {
  const int* ids = (const int*)d_in[0];
  const float* emb = (const float*)d_in[1];
  const float* w_ih = (const float*)d_in[2];
  const float* w_hh = (const float*)d_in[3];
  const float* b_ih = (const float*)d_in[4];
  const float* b_hh = (const float*)d_in[5];
  const float* gamma = (const float*)d_in[6];
  const float* beta = (const float*)d_in[7];
  const float* head_w = (const float*)d_in[8];
  const float* head_b = (const float*)d_in[9];
  float* out = (float*)d_out;

  char* ws = (char*)d_ws;
  size_t off = 0;
  auto alloc = [&](size_t bytes) -> void* {
    void* p = ws + off;
    off = (off + bytes + 255) & ~(size_t)255;
    return p;
  };
  unsigned short* h_state = (unsigned short*)alloc(2 * 16 * HID * 2);
  unsigned short* A1 = (unsigned short*)alloc((size_t)NB * SEQ * HID * 2);
  unsigned short* wihb = (unsigned short*)alloc((size_t)NG * HID * 2);
  unsigned short* hwb = (unsigned short*)alloc((size_t)VOCAB * HID * 2);
  float* xg = (float*)alloc((size_t)NB * SEQ * NG * 4);
  float* hsb = (float*)alloc((size_t)NB * SEQ * HID * 4);
  unsigned short* yb = (unsigned short*)alloc((size_t)NB * SEQ * HID * 2);

  init_ws_kernel<<<64, 256, 0, stream>>>(h_state);
  conv_bf16_kernel<<<(NG * HID / 4) / 256, 256, 0, stream>>>(w_ih, wihb,
                                                             NG * HID / 4);
  conv_bf16_kernel<<<(VOCAB * HID / 4) / 256, 256, 0, stream>>>(
      head_w, hwb, VOCAB * HID / 4);
  embed_kernel<<<NB * SEQ, 256, 0, stream>>>(ids, emb, A1);
  // xg = A1 * w_ih^T + b_ih : M=4096, N=1536  (grid 32*12=384, %8==0)
  gemm_bt_kernel<<<(NB * SEQ / BM) * (NG / BN), 256, 0, stream>>>(
      A1, wihb, b_ih, xg, NG, NG / BN);
  gru_kernel<<<GRU_WGS, 192, 0, stream>>>(xg, w_hh, b_hh, hsb, h_state);
  ln_kernel<<<NB * SEQ / 4, 256, 0, stream>>>(hsb, gamma, beta, yb);
  // logits = y * head_w^T + head_b : M=4096, N=32000 (grid 32*250=8000, %8==0)
  gemm_bt_kernel<<<(NB * SEQ / BM) * (VOCAB / BN), 256, 0, stream>>>(
      yb, hwb, head_b, out, VOCAB, VOCAB / BN);
}

// Round 5
// 1724.070 us; speedup vs baseline: 1.4027x; 1.4027x over previous
//
#include <hip/hip_runtime.h>
#include <hip/hip_bf16.h>
#include <stdint.h>

#define VOCAB 32000
#define HID 512
#define NB 8
#define SEQ 512
#define NG 1536
#define LN_EPS 1e-5f
#define GRU_WGS 32
#define GRU_SPIN_BUDGET (1 << 20)

typedef short bf16x8 __attribute__((ext_vector_type(8)));
typedef float f32x4 __attribute__((ext_vector_type(4)));

__device__ __forceinline__ unsigned short f2bf(float f) {
  union { float f; uint32_t u; } c; c.f = f;
  return (unsigned short)((c.u + 0x7fffu + ((c.u >> 16) & 1u)) >> 16);
}

// ---------------- init workspace (every launch: h_state=0, flags=0) ---------
__global__ void init_ws_kernel(unsigned short* h_state, int* flags) {
  int i = blockIdx.x * 256 + threadIdx.x;
  if (i < 2 * 16 * HID) h_state[i] = 0;
  if (i < GRU_WGS * 16) flags[i] = 0;
}

// ---------------- fp32 -> bf16 bulk convert ---------------------------------
__global__ void conv_bf16_kernel(const float* __restrict__ in,
                                 unsigned short* __restrict__ out, int n4) {
  int i = blockIdx.x * 256 + threadIdx.x;
  if (i >= n4) return;
  const float4 v = ((const float4*)in)[i];
  ushort4 o;
  o.x = f2bf(v.x); o.y = f2bf(v.y); o.z = f2bf(v.z); o.w = f2bf(v.w);
  ((ushort4*)out)[i] = o;
}

// ---------------- embedding gather -> bf16 A matrix [4096][512] -------------
__global__ void embed_kernel(const int* __restrict__ ids,
                             const float* __restrict__ emb,
                             unsigned short* __restrict__ out) {
  int row = blockIdx.x;
  int id = ids[row];
  int c = threadIdx.x * 2;
  const float2 v = *(const float2*)(emb + (size_t)id * HID + c);
  ushort2 o; o.x = f2bf(v.x); o.y = f2bf(v.y);
  *(ushort2*)(out + (size_t)row * HID + c) = o;
}

// ---------------- bf16 GEMM: C[M][N] = A[M][K] * B[N][K]^T + bias -----------
#define BM 128
#define BN 128
#define BK 32

__global__ __launch_bounds__(256, 2) void gemm_bt_kernel(
    const unsigned short* __restrict__ A, const unsigned short* __restrict__ B,
    const float* __restrict__ bias, float* __restrict__ C, int N, int nbn) {
  __shared__ unsigned short a_lds[BM * BK];
  __shared__ unsigned short b_lds[BN * BK];
  const int nwg = gridDim.x;
  const int chunk = nwg >> 3;
  const int bid = blockIdx.x;
  const int sw = (bid & 7) * chunk + (bid >> 3);
  const int bm = sw / nbn, bn = sw % nbn;
  const int tid = threadIdx.x;
  const int lane = tid & 63, wid = tid >> 6;
  const int wm = wid >> 1, wn = wid & 1;

  f32x4 acc[4][4] = {};

  for (int kt = 0; kt < HID / BK; ++kt) {
    __syncthreads();
#pragma unroll
    for (int p = 0; p < 2; ++p) {
      const int flat = (p * 256 + tid) * 16;  // byte offset in 8KB tile
      const int row = flat >> 6;              // 64B per row (32 bf16)
      const int kb = flat & 63;
      const char* ga =
          (const char*)(A + ((size_t)(bm * BM + row) * HID + kt * BK)) + kb;
      const char* gb =
          (const char*)(B + ((size_t)(bn * BN + row) * HID + kt * BK)) + kb;
      char* la = (char*)a_lds + (size_t)(p * 256 + wid * 64) * 16;
      char* lb = (char*)b_lds + (size_t)(p * 256 + wid * 64) * 16;
      __builtin_amdgcn_global_load_lds(
          (const __attribute__((address_space(1))) void*)ga,
          (__attribute__((address_space(3))) void*)la, 16, 0, 0);
      __builtin_amdgcn_global_load_lds(
          (const __attribute__((address_space(1))) void*)gb,
          (__attribute__((address_space(3))) void*)lb, 16, 0, 0);
    }
    __syncthreads();
    bf16x8 af[4], bfr[4];
#pragma unroll
    for (int i = 0; i < 4; ++i) {
      af[i] = *(const bf16x8*)(a_lds + (wm * 64 + i * 16 + (lane & 15)) * BK +
                               (lane >> 4) * 8);
      bfr[i] = *(const bf16x8*)(b_lds + (wn * 64 + i * 16 + (lane & 15)) * BK +
                                (lane >> 4) * 8);
    }
#pragma unroll
    for (int i = 0; i < 4; ++i)
#pragma unroll
      for (int j = 0; j < 4; ++j)
        acc[i][j] =
            __builtin_amdgcn_mfma_f32_16x16x32_bf16(af[i], bfr[j], acc[i][j], 0, 0, 0);
  }
#pragma unroll
  for (int i = 0; i < 4; ++i) {
    const int mrow = bm * BM + wm * 64 + i * 16 + (lane >> 4) * 4;
#pragma unroll
    for (int j = 0; j < 4; ++j) {
      const int col = bn * BN + wn * 64 + j * 16 + (lane & 15);
      const float bv = bias[col];
#pragma unroll
      for (int r = 0; r < 4; ++r)
        C[(size_t)(mrow + r) * N + col] = acc[i][j][r] + bv;
    }
  }
}

// ---------------- persistent GRU scan: 1 wave per WG -------------------------
// 32 WGs x 64 threads (ONE wave). WG w owns h cols [w*16, w*16+16).
// The single wave holds ALL THREE gates' w_hh rows as 48 B-frags (~300 VGPR,
// 1 wave/SIMD). C-layout (col=lane&15, row=(lane>>4)*4+r) puts r/z/n for the
// same (batch,col) in the SAME lane -> gate math fully in-register, ZERO
// barriers per step. LDS used only for a barrier-free within-wave transpose
// before publish. Flag protocol (round-3): publish bf16 h -> s_waitcnt
// vmcnt(0) -> lane0 bumps flag -> consumers poll 32 flags (1 dword/lane),
// then bulk-load h once. All cross-WG ops relaxed agent-scope (LLC, no cache
// maintenance). h double-buffered; max skew 1 step (proof: WG B passes poll
// t+1 only after A's flag>=t+1, set after A's reads of buf[t&1] completed).
__global__ __launch_bounds__(64, 1) void gru_kernel(
    const float* __restrict__ xg, const float* __restrict__ w_hh,
    const float* __restrict__ b_hh, float* __restrict__ hs,
    unsigned short* h_state, int* flags) {
  const int wid = blockIdx.x;
  const int lane = threadIdx.x;
  const int col16 = lane & 15;
  const int kq = lane >> 4;  // 0..3 : which 8-wide K slice of the 32-window

  __shared__ float h_pub[8][16];

  // pack all 3 gates' weights into 48 MFMA B-fragments (registers), once
  bf16x8 wf[3][16];
#pragma unroll
  for (int g = 0; g < 3; ++g) {
    const float* wr =
        w_hh + (size_t)(g * HID + wid * 16 + col16) * HID + kq * 8;
#pragma unroll
    for (int kk = 0; kk < 16; ++kk) {
      float4 f0 = *(const float4*)(wr + kk * 32);
      float4 f1 = *(const float4*)(wr + kk * 32 + 4);
      bf16x8 v;
      v[0] = (short)f2bf(f0.x); v[1] = (short)f2bf(f0.y);
      v[2] = (short)f2bf(f0.z); v[3] = (short)f2bf(f0.w);
      v[4] = (short)f2bf(f1.x); v[5] = (short)f2bf(f1.y);
      v[6] = (short)f2bf(f1.z); v[7] = (short)f2bf(f1.w);
      wf[g][kk] = v;
    }
  }
  const float bh_r = b_hh[0 * HID + wid * 16 + col16];
  const float bh_z = b_hh[1 * HID + wid * 16 + col16];
  const float bh_n = b_hh[2 * HID + wid * 16 + col16];

  const int abase = col16 * HID + kq * 8;  // A-frag: row=batch=col16, k=kq*8
  const bool realrow = col16 < 8;          // batches 8..15 are padding zeros
  const bool owner = lane < 32;            // lanes 0..31 own real (batch,col)
  const int bbase = kq * 4;                // first batch of this lane's C rows

  // per-lane xg for 4 batches (prefetched); lanes>=32 unused
  float xr[4], xz[4], xn[4];
#pragma unroll
  for (int r = 0; r < 4; ++r) { xr[r] = 0.f; xz[r] = 0.f; xn[r] = 0.f; }
  if (owner) {
#pragma unroll
    for (int r = 0; r < 4; ++r) {
      const size_t xo = (size_t)(bbase + r) * SEQ * NG + wid * 16 + col16;
      xr[r] = xg[xo];
      xz[r] = xg[xo + HID];
      xn[r] = xg[xo + 2 * HID];
    }
  }
  float hprev[4] = {0.f, 0.f, 0.f, 0.f};
  int budget = GRU_SPIN_BUDGET;

  for (int t = 0; t < SEQ; ++t) {
    // ---- wait for h_t (flags >= t); all 64 lanes in the ballot ----
    while (budget > 0) {
      int v = t;
      if (lane < 32)
        v = __hip_atomic_load(flags + lane * 16, __ATOMIC_RELAXED,
                              __HIP_MEMORY_SCOPE_AGENT);
      if (__ballot(v >= t) == ~0ULL) break;
      --budget;
      __builtin_amdgcn_s_sleep(1);
    }

    const unsigned short* rd = h_state + (size_t)(t & 1) * (16 * HID);
    unsigned short* wpub = h_state + (size_t)((t + 1) & 1) * (16 * HID);

    // ---- bulk-load A fragments (one shot, all independent) ----
    uint64_t hb[32];
#pragma unroll
    for (int kk = 0; kk < 32; ++kk) hb[kk] = 0;
    if (realrow) {
#pragma unroll
      for (int kk = 0; kk < 16; ++kk) {
        const uint64_t* ap = (const uint64_t*)(rd + abase + kk * 32);
        hb[2 * kk] =
            __hip_atomic_load(ap, __ATOMIC_RELAXED, __HIP_MEMORY_SCOPE_AGENT);
        hb[2 * kk + 1] = __hip_atomic_load(ap + 1, __ATOMIC_RELAXED,
                                           __HIP_MEMORY_SCOPE_AGENT);
      }
    }

    // ---- three independent 16-deep MFMA chains (r, z, n) ----
    f32x4 ar = {0.f, 0.f, 0.f, 0.f};
    f32x4 az = {0.f, 0.f, 0.f, 0.f};
    f32x4 an = {0.f, 0.f, 0.f, 0.f};
#pragma unroll
    for (int kk = 0; kk < 16; ++kk) {
      union { uint64_t u[2]; bf16x8 v; } cv;
      cv.u[0] = hb[2 * kk]; cv.u[1] = hb[2 * kk + 1];
      ar = __builtin_amdgcn_mfma_f32_16x16x32_bf16(cv.v, wf[0][kk], ar, 0, 0, 0);
      az = __builtin_amdgcn_mfma_f32_16x16x32_bf16(cv.v, wf[1][kk], az, 0, 0, 0);
      an = __builtin_amdgcn_mfma_f32_16x16x32_bf16(cv.v, wf[2][kk], an, 0, 0, 0);
    }

    // ---- in-register gate math: lane owns (batch bbase+r, col col16) ----
    float hnew[4];
    if (owner) {
#pragma unroll
      for (int r = 0; r < 4; ++r) {
        const float rg = 1.f / (1.f + __expf(-(xr[r] + ar[r] + bh_r)));
        const float zg = 1.f / (1.f + __expf(-(xz[r] + az[r] + bh_z)));
        const float a = xn[r] + rg * (an[r] + bh_n);
        const float e2 = __expf(-2.f * fabsf(a));
        const float nn = copysignf((1.f - e2) / (1.f + e2), a);
        hnew[r] = (1.f - zg) * nn + zg * hprev[r];
        hprev[r] = hnew[r];
        h_pub[bbase + r][col16] = hnew[r];
      }
    }
    asm volatile("" ::: "memory");  // keep ds_writes before ds_reads
    // ---- barrier-free within-wave transpose + tagged publish ----
    {
      const int tb = lane >> 3;          // batch 0..7
      const int tc = (lane & 7) * 2;     // even col of the pair
      const float2 hp = *(const float2*)&h_pub[tb][tc];
      union { unsigned short s[2]; uint32_t u; } pk;
      pk.s[0] = f2bf(hp.x);
      pk.s[1] = f2bf(hp.y);
      uint32_t* dst = (uint32_t*)(wpub + tb * HID + wid * 16 + tc);
      __hip_atomic_store(dst, pk.u, __ATOMIC_RELAXED,
                         __HIP_MEMORY_SCOPE_AGENT);
    }
    asm volatile("s_waitcnt vmcnt(0)" ::: "memory");  // drain publish stores
    if (lane == 0)
      __hip_atomic_store(flags + wid * 16, t + 1, __ATOMIC_RELAXED,
                         __HIP_MEMORY_SCOPE_AGENT);
    // ---- off-critical-path: hs output + next xg prefetch ----
    if (owner) {
#pragma unroll
      for (int r = 0; r < 4; ++r)
        hs[((size_t)(bbase + r) * SEQ + t) * HID + wid * 16 + col16] = hnew[r];
      if (t + 1 < SEQ) {
#pragma unroll
        for (int r = 0; r < 4; ++r) {
          const size_t xo = (size_t)(bbase + r) * SEQ * NG +
                            (size_t)(t + 1) * NG + wid * 16 + col16;
          xr[r] = xg[xo];
          xz[r] = xg[xo + HID];
          xn[r] = xg[xo + 2 * HID];
        }
      }
    }
  }
}

// ---------------- LayerNorm rows of 512 -> bf16 ------------------------------
__global__ __launch_bounds__(256) void ln_kernel(
    const float* __restrict__ hs, const float* __restrict__ gamma,
    const float* __restrict__ beta, unsigned short* __restrict__ y) {
  const int row = blockIdx.x * 4 + (threadIdx.x >> 6);
  const int lane = threadIdx.x & 63;
  const float* x = hs + (size_t)row * HID + lane * 8;
  float v[8];
  *(float4*)v = *(const float4*)x;
  *(float4*)(v + 4) = *(const float4*)(x + 4);
  float s = 0.f, q = 0.f;
#pragma unroll
  for (int j = 0; j < 8; ++j) { s += v[j]; q += v[j] * v[j]; }
#pragma unroll
  for (int off = 32; off > 0; off >>= 1) {
    s += __shfl_xor(s, off);
    q += __shfl_xor(q, off);
  }
  const float mu = s * (1.f / 512.f);
  const float is = rsqrtf(q * (1.f / 512.f) - mu * mu + LN_EPS);
  const float* gp = gamma + lane * 8;
  const float* bp = beta + lane * 8;
  union { unsigned short o[8]; uint4 u; } pk;
#pragma unroll
  for (int j = 0; j < 8; ++j) pk.o[j] = f2bf((v[j] - mu) * is * gp[j] + bp[j]);
  *(uint4*)(y + (size_t)row * HID + lane * 8) = pk.u;
}

// ---------------- launch -----------------------------------------------------
extern "C" void kernel_launch(void* const* d_in, const int* in_sizes, int n_in,
                              void* d_out, int out_size, void* d_ws,
                              size_t ws_size, hipStream_t stream) {
  const int* ids = (const int*)d_in[0];
  const float* emb = (const float*)d_in[1];
  const float* w_ih = (const float*)d_in[2];
  const float* w_hh = (const float*)d_in[3];
  const float* b_ih = (const float*)d_in[4];
  const float* b_hh = (const float*)d_in[5];
  const float* gamma = (const float*)d_in[6];
  const float* beta = (const float*)d_in[7];
  const float* head_w = (const float*)d_in[8];
  const float* head_b = (const float*)d_in[9];
  float* out = (float*)d_out;

  char* ws = (char*)d_ws;
  size_t off = 0;
  auto alloc = [&](size_t bytes) -> void* {
    void* p = ws + off;
    off = (off + bytes + 255) & ~(size_t)255;
    return p;
  };
  int* flags = (int*)alloc(GRU_WGS * 16 * sizeof(int));
  unsigned short* h_state = (unsigned short*)alloc(2 * 16 * HID * 2);
  unsigned short* A1 = (unsigned short*)alloc((size_t)NB * SEQ * HID * 2);
  unsigned short* wihb = (unsigned short*)alloc((size_t)NG * HID * 2);
  unsigned short* hwb = (unsigned short*)alloc((size_t)VOCAB * HID * 2);
  float* xg = (float*)alloc((size_t)NB * SEQ * NG * 4);
  float* hsb = (float*)alloc((size_t)NB * SEQ * HID * 4);
  unsigned short* yb = (unsigned short*)alloc((size_t)NB * SEQ * HID * 2);

  init_ws_kernel<<<64, 256, 0, stream>>>(h_state, flags);
  conv_bf16_kernel<<<(NG * HID / 4) / 256, 256, 0, stream>>>(w_ih, wihb,
                                                             NG * HID / 4);
  conv_bf16_kernel<<<(VOCAB * HID / 4) / 256, 256, 0, stream>>>(
      head_w, hwb, VOCAB * HID / 4);
  embed_kernel<<<NB * SEQ, 256, 0, stream>>>(ids, emb, A1);
  // xg = A1 * w_ih^T + b_ih : M=4096, N=1536  (grid 32*12=384, %8==0)
  gemm_bt_kernel<<<(NB * SEQ / BM) * (NG / BN), 256, 0, stream>>>(
      A1, wihb, b_ih, xg, NG, NG / BN);
  gru_kernel<<<GRU_WGS, 64, 0, stream>>>(xg, w_hh, b_hh, hsb, h_state, flags);
  ln_kernel<<<NB * SEQ / 4, 256, 0, stream>>>(hsb, gamma, beta, yb);
  // logits = y * head_w^T + head_b : M=4096, N=32000 (grid 32*250=8000, %8==0)
  gemm_bt_kernel<<<(NB * SEQ / BM) * (VOCAB / BN), 256, 0, stream>>>(
      yb, hwb, head_b, out, VOCAB, VOCAB / BN);
}